// Round 1
// 93.582 us; speedup vs baseline: 1.0357x; 1.0357x over previous
//
#include <hip/hip_runtime.h>
#include <math.h>

// ---------------------------------------------------------------------------
// Single fused kernel. The 7 scalar constants from the algebraic collapse
// are recomputed redundantly per block (weights are ~25 KB, L2-resident
// after the first wave of blocks), so NO workspace and NO second launch.
//
// Algebra (verified in previous session):
//   tokens rank-1 in scalar feature => scores separable =>
//   softmax row collapses to scalar S; final y = c0 + c1*S_AB + c2*S_BA.
// ---------------------------------------------------------------------------

__device__ __forceinline__ float sigmoidf_(float x) {
    return 1.0f / (1.0f + expf(-x));
}

__device__ __forceinline__ float one_elem(
    float a0, float a1, float a2, float b0, float b1,
    float kaAB, float kgAB, float kaBA, float kgBA,
    float c0, float c1, float c2)
{
    // --- S_AB: 3 queries (a_i), 2 keys (b_j); 2-key softmax == sigmoid ---
    const float dB = b0 - b1;
    const float s0 = b1 + dB * sigmoidf_(dB * fmaf(kaAB, a0, kgAB));
    const float s1 = b1 + dB * sigmoidf_(dB * fmaf(kaAB, a1, kgAB));
    const float s2 = b1 + dB * sigmoidf_(dB * fmaf(kaAB, a2, kgAB));
    const float S_AB = (s0 + s1 + s2) * (1.0f / 3.0f);

    // --- S_BA: 2 queries (b_j), 3 keys (a_i) ---
    float S_BA = 0.f;
    #pragma unroll
    for (int j = 0; j < 2; ++j) {
        const float bj = (j == 0) ? b0 : b1;
        const float c = fmaf(kaBA, bj, kgBA);
        const float l0 = a0 * c, l1 = a1 * c, l2 = a2 * c;
        const float m = fmaxf(l0, fmaxf(l1, l2));
        const float e0 = expf(l0 - m), e1 = expf(l1 - m), e2 = expf(l2 - m);
        S_BA += (e0 * a0 + e1 * a1 + e2 * a2) / (e0 + e1 + e2);
    }
    S_BA *= 0.5f;

    const float y = fmaf(c1, S_AB, fmaf(c2, S_BA, c0));
    return (y >= 0.f) ? y : 0.01f * y;
}

__global__ __launch_bounds__(256) void fused_all(
    const float* __restrict__ Af,  // [n,3]
    const float* __restrict__ Bf,  // [n,2]
    const float* __restrict__ WA, const float* __restrict__ bA,
    const float* __restrict__ WB, const float* __restrict__ bB,
    const float* __restrict__ WiAB, const float* __restrict__ biAB,
    const float* __restrict__ WoAB, const float* __restrict__ boAB,
    const float* __restrict__ WiBA, const float* __restrict__ biBA,
    const float* __restrict__ WoBA, const float* __restrict__ boBA,
    const float* __restrict__ Wf, const float* __restrict__ bf,
    float* __restrict__ out, int n)
{
    __shared__ float uq[2][32], uk[2][32], cq[2][32], uv[2][32], cv[2][32];
    __shared__ float p[2][32], r[2][32];
    __shared__ float cst[7];

    const int tid = threadIdx.x;

    // ---- prologue phase 1: in_proj collapse (wave 0: s = side, e = row) ----
    if (tid < 64) {
        const int s = tid >> 5;            // 0 = AB, 1 = BA
        const int e = tid & 31;
        const float* Wi     = s ? WiBA : WiAB;
        const float* bi     = s ? biBA : biAB;
        const float* wq_vec = s ? WB : WA; // query-side token weight
        const float* bq_vec = s ? bB : bA;
        const float* wk_vec = s ? WA : WB; // key/value-side token weight
        const float* bk_vec = s ? bA : bB;
        float s_uq = 0.f, s_uk = 0.f, s_cq = 0.f, s_uv = 0.f, s_cv = 0.f;
        #pragma unroll
        for (int d = 0; d < 32; ++d) {
            const float wq = Wi[e * 32 + d];
            const float wk = Wi[(32 + e) * 32 + d];
            const float wv = Wi[(64 + e) * 32 + d];
            s_uq += wq * wq_vec[d];
            s_cq += wq * bq_vec[d];
            s_uk += wk * wk_vec[d];
            s_uv += wv * wk_vec[d];
            s_cv += wv * bk_vec[d];
        }
        uq[s][e] = s_uq; uk[s][e] = s_uk;
        cq[s][e] = s_cq + bi[e];
        uv[s][e] = s_uv; cv[s][e] = s_cv + bi[64 + e];
    }
    __syncthreads();

    // ---- prologue phase 2: out_proj collapse ----
    if (tid < 64) {
        const int s = tid >> 5;
        const int e = tid & 31;
        const float* Wo = s ? WoBA : WoAB;
        const float* bo = s ? boBA : boAB;
        float sp = 0.f, sr = 0.f;
        #pragma unroll
        for (int d = 0; d < 32; ++d) {
            const float w = Wo[e * 32 + d];
            sp += w * uv[s][d];
            sr += w * cv[s][d];
        }
        p[s][e] = sp; r[s][e] = sr + bo[e];
    }
    __syncthreads();

    // ---- prologue phase 3: 7 scalars via width-32 shuffle reduction ----
    if (tid < 32) {
        const int d = tid;
        float vaAB = uq[0][d] * uk[0][d];
        float vgAB = cq[0][d] * uk[0][d];
        float vaBA = uq[1][d] * uk[1][d];
        float vgBA = cq[1][d] * uk[1][d];
        const float wf = Wf[d];
        float vc1 = wf * p[0][d];
        float vc2 = wf * p[1][d];
        float vc0 = wf * (r[0][d] + r[1][d]);
        #pragma unroll
        for (int off = 16; off > 0; off >>= 1) {
            vaAB += __shfl_down(vaAB, off, 32);
            vgAB += __shfl_down(vgAB, off, 32);
            vaBA += __shfl_down(vaBA, off, 32);
            vgBA += __shfl_down(vgBA, off, 32);
            vc1  += __shfl_down(vc1,  off, 32);
            vc2  += __shfl_down(vc2,  off, 32);
            vc0  += __shfl_down(vc0,  off, 32);
        }
        if (d == 0) {
            const float inv_sqrt_e = 0.17677669529663688f; // 1/sqrt(32)
            cst[0] = vaAB * inv_sqrt_e;
            cst[1] = vgAB * inv_sqrt_e;
            cst[2] = vaBA * inv_sqrt_e;
            cst[3] = vgBA * inv_sqrt_e;
            cst[4] = 0.5f * vc0 + bf[0];
            cst[5] = 0.5f * vc1;
            cst[6] = 0.5f * vc2;
        }
    }
    __syncthreads();

    const float kaAB = cst[0], kgAB = cst[1];
    const float kaBA = cst[2], kgBA = cst[3];
    const float c0 = cst[4], c1 = cst[5], c2 = cst[6];

    // ---- main: 4 elements per thread, fully float4-vectorized ----
    const int q = blockIdx.x * blockDim.x + tid;   // quad index
    const int base = q * 4;

    if (base + 3 < n) {
        const float4 af0 = *reinterpret_cast<const float4*>(Af + 3 * base);
        const float4 af1 = *reinterpret_cast<const float4*>(Af + 3 * base + 4);
        const float4 af2 = *reinterpret_cast<const float4*>(Af + 3 * base + 8);
        const float4 bf0 = *reinterpret_cast<const float4*>(Bf + 2 * base);
        const float4 bf1 = *reinterpret_cast<const float4*>(Bf + 2 * base + 4);

        float4 o;
        o.x = one_elem(af0.x, af0.y, af0.z, bf0.x, bf0.y,
                       kaAB, kgAB, kaBA, kgBA, c0, c1, c2);
        o.y = one_elem(af0.w, af1.x, af1.y, bf0.z, bf0.w,
                       kaAB, kgAB, kaBA, kgBA, c0, c1, c2);
        o.z = one_elem(af1.z, af1.w, af2.x, bf1.x, bf1.y,
                       kaAB, kgAB, kaBA, kgBA, c0, c1, c2);
        o.w = one_elem(af2.y, af2.z, af2.w, bf1.z, bf1.w,
                       kaAB, kgAB, kaBA, kgBA, c0, c1, c2);
        *reinterpret_cast<float4*>(out + base) = o;
    } else {
        for (int i = base; i < n; ++i) {
            const float a0 = Af[3 * i + 0];
            const float a1 = Af[3 * i + 1];
            const float a2 = Af[3 * i + 2];
            const float b0 = Bf[2 * i + 0];
            const float b1 = Bf[2 * i + 1];
            out[i] = one_elem(a0, a1, a2, b0, b1,
                              kaAB, kgAB, kaBA, kgBA, c0, c1, c2);
        }
    }
}

extern "C" void kernel_launch(void* const* d_in, const int* in_sizes, int n_in,
                              void* d_out, int out_size, void* d_ws, size_t ws_size,
                              hipStream_t stream) {
    const float* groupA = (const float*)d_in[0];   // [B,3]
    const float* groupB = (const float*)d_in[1];   // [B,2]
    const float* WA   = (const float*)d_in[2];     // [32,1]
    const float* bA   = (const float*)d_in[3];     // [32]
    const float* WB   = (const float*)d_in[4];
    const float* bB   = (const float*)d_in[5];
    const float* WiAB = (const float*)d_in[6];     // [96,32]
    const float* biAB = (const float*)d_in[7];     // [96]
    const float* WoAB = (const float*)d_in[8];     // [32,32]
    const float* boAB = (const float*)d_in[9];     // [32]
    const float* WiBA = (const float*)d_in[10];
    const float* biBA = (const float*)d_in[11];
    const float* WoBA = (const float*)d_in[12];
    const float* boBA = (const float*)d_in[13];
    const float* Wf   = (const float*)d_in[14];    // [1,32]
    const float* bf   = (const float*)d_in[15];    // [1]

    float* out = (float*)d_out;
    const int n = in_sizes[0] / 3;                 // B

    const int block = 256;
    const int nq = (n + 3) >> 2;                   // quads
    const int grid = (nq + block - 1) / block;     // 512 blocks at B=524288

    fused_all<<<grid, block, 0, stream>>>(
        groupA, groupB, WA, bA, WB, bB,
        WiAB, biAB, WoAB, boAB, WiBA, biBA, WoBA, boBA,
        Wf, bf, out, n);
    // NOTE: d_ws deliberately untouched — the 256 MiB workspace re-poison
    // fills dominated the previous profile (5× ~41 µs fillBufferAligned).
}